// Round 6
// baseline (206.256 us; speedup 1.0000x reference)
//
#include <hip/hip_runtime.h>
#include <math.h>

// x: [64, 256, 32, 32] fp32.
// 3-kernel pipeline, all phases at full occupancy:
//  S: 2048 blocks x 256  — partial channel sums + threshold-candidates -> ws
//  T:  256 blocks x 256  — mean, exact select of v_K among candidates (LDS),
//                          validity proven exactly, global fallback; -> alpha/beta
//  A: 2048 blocks x 256  — out = x*alpha + beta (x L3-hot), nontemporal stores
#define C_DIM    256
#define N_DIM    64
#define M_DIM    65536
#define K_TOP    100
#define EPS_F    1e-7f
#define THREADS  256
#define NWAVES   4
#define T_FAST   2.5f           // candidate threshold; validity checked exactly
#define SBLOCKS  2048
#define ABLOCKS  2048
#define MAXCAP   4096u

// ws layout (bytes)
#define WS_CNT_OFF   0          // 256 u32  per-channel candidate counters
#define WS_PART_OFF  1024       // 2048 double  per-S-block partial sums
#define WS_AB_OFF    17408      // 512 float    alpha[256] ++ beta[256]
#define WS_CAND_OFF  20480      // 256 * cap2 u32 candidate raw-bits

typedef float f4v __attribute__((ext_vector_type(4)));

__device__ __forceinline__ unsigned int wave_suffix_u32(unsigned int v, int lane)
{
    #pragma unroll
    for (int off = 1; off < 64; off <<= 1) {
        unsigned int o = __shfl_down(v, off, 64);
        if (lane + off < 64) v += o;
    }
    return v;   // suffix-inclusive sum over lanes >= lane
}

__device__ __forceinline__ double block_sum_double(double v, double* dred, int tid)
{
    const int lane = tid & 63, wv = tid >> 6;
    #pragma unroll
    for (int off = 1; off < 64; off <<= 1) {
        double o = __shfl_down(v, off, 64);
        if (lane + off < 64) v += o;
    }
    __syncthreads();
    if (lane == 0) dred[wv] = v;
    __syncthreads();
    double r = 0.0;
    if (tid == 0) {
        #pragma unroll
        for (int i = 0; i < NWAVES; ++i) r += dred[i];
    }
    return r;   // valid on tid 0 only
}

// Find, in hist[0..nbins) (ascending bins), the bin holding the Krem-th
// largest element; write bin + count-strictly-above into LDS outs.
__device__ __forceinline__ void select_bin(
    const unsigned int* hist, int nbins, unsigned int Krem,
    unsigned int* wtot, unsigned int* wsuf,
    unsigned int* out_bin, unsigned int* out_cnt, int tid)
{
    const int lane = tid & 63, wv = tid >> 6;
    const int bpt = (nbins + THREADS - 1) / THREADS;
    const int lo = tid * bpt;
    const int hi = min(nbins, lo + bpt);
    unsigned int s = 0;
    for (int b = lo; b < hi; ++b) s += hist[b];
    const unsigned int ws = wave_suffix_u32(s, lane);
    if (lane == 0) wtot[wv] = ws;
    __syncthreads();
    if (tid < NWAVES) {
        unsigned int t2 = 0;
        for (int j = tid; j < NWAVES; ++j) t2 += wtot[j];
        wsuf[tid] = t2;
    }
    __syncthreads();
    const unsigned int above_w = (wv + 1 < NWAVES) ? wsuf[wv + 1] : 0u;
    const unsigned int incl   = ws + above_w;
    const unsigned int S_excl = incl - s;
    if (S_excl < Krem && incl >= Krem) {     // exactly one thread
        unsigned int cum = S_excl;
        for (int b = hi - 1; b >= lo; --b) {
            unsigned int h = hist[b];
            if (cum + h >= Krem) { *out_bin = (unsigned int)b; *out_cnt = cum; break; }
            cum += h;
        }
    }
    __syncthreads();
}

// ---------------------------------------------------------------------------
// S: partial sums + candidate collection. block b -> channel c=b&255, group
// g=b>>8 covering n = 8g..8g+7. Thread t reads float4 (n*256+c)*256 + t.
// ---------------------------------------------------------------------------
__global__ __launch_bounds__(THREADS) void stats_pass(
    const float4* __restrict__ x4, double* __restrict__ partial,
    unsigned int* __restrict__ cnt, unsigned int* __restrict__ candbuf,
    unsigned int cap2)
{
    const int b = blockIdx.x;
    const int c = b & 255;
    const int g = b >> 8;
    const int t = threadIdx.x;
    __shared__ double dred[NWAVES];
    unsigned int* dst = candbuf + (size_t)c * cap2;

    double s = 0.0;
    #pragma unroll
    for (int j = 0; j < 8; ++j) {
        const int n = (g << 3) + j;
        const float4 q = x4[((size_t)((n << 8) + c) << 8) + t];
        s += ((double)q.x + (double)q.y) + ((double)q.z + (double)q.w);
        const bool p0 = fabsf(q.x) >= T_FAST, p1 = fabsf(q.y) >= T_FAST;
        const bool p2 = fabsf(q.z) >= T_FAST, p3 = fabsf(q.w) >= T_FAST;
        const int nl = (int)p0 + (int)p1 + (int)p2 + (int)p3;
        if (nl) {
            unsigned int p = atomicAdd(&cnt[c], (unsigned int)nl);
            if (p0) { if (p < cap2) dst[p] = __float_as_uint(q.x); ++p; }
            if (p1) { if (p < cap2) dst[p] = __float_as_uint(q.y); ++p; }
            if (p2) { if (p < cap2) dst[p] = __float_as_uint(q.z); ++p; }
            if (p3) { if (p < cap2) dst[p] = __float_as_uint(q.w); ++p; }
        }
    }
    const int lane = t & 63, wv = t >> 6;
    #pragma unroll
    for (int off = 1; off < 64; off <<= 1) {
        double o = __shfl_down(s, off, 64);
        if (lane + off < 64) s += o;
    }
    if (lane == 0) dred[wv] = s;
    __syncthreads();
    if (t == 0) partial[b] = (dred[0] + dred[1]) + (dred[2] + dred[3]);
}

// ---------------------------------------------------------------------------
// T: per-channel select. One 256-thread block per channel.
// ---------------------------------------------------------------------------
__global__ __launch_bounds__(THREADS) void select_pass(
    const float4* __restrict__ x4, const double* __restrict__ partial,
    const unsigned int* __restrict__ cnt, const unsigned int* __restrict__ candbuf,
    unsigned int cap2,
    const float* __restrict__ weight, const float* __restrict__ bias,
    float* __restrict__ ab, float cconst)
{
    const int c = blockIdx.x;
    const int t = threadIdx.x;

    __shared__ unsigned int ubits[MAXCAP];
    __shared__ unsigned int hist[4096];
    __shared__ unsigned int wtot[NWAVES], wsuf[NWAVES];
    __shared__ double dred[NWAVES > 8 ? NWAVES : 8];
    __shared__ float s_mean;
    __shared__ unsigned int s_bin, s_cnt, s_nB;

    if (t < 8) dred[t] = partial[(t << 8) + c];
    if (t == 0) s_nB = 0u;
    __syncthreads();
    if (t == 0) {
        double m = 0.0;
        #pragma unroll
        for (int i = 0; i < 8; ++i) m += dred[i];
        s_mean = (float)(m / (double)M_DIM);
    }
    __syncthreads();
    const float mean = s_mean;
    const float Babs = T_FAST + fabsf(mean);
    const unsigned int Bbits = __float_as_uint(Babs);
    const unsigned int n = cnt[c];

    // Validity: non-collected values have |x-mean| < Babs; if >= K collected
    // values exceed Babs (strict), the global top-K is inside the collection.
    bool fast = (n <= cap2);
    if (fast) {
        unsigned int loc = 0;
        for (unsigned int i = t; i < n; i += THREADS) {
            const float v = __uint_as_float(candbuf[(size_t)c * cap2 + i]);
            const unsigned int u = __float_as_uint(fabsf(v - mean));
            ubits[i] = u;
            if (u > Bbits) ++loc;
        }
        if (loc) atomicAdd(&s_nB, loc);
        __syncthreads();
        fast = (s_nB >= K_TOP);
    }

    unsigned int vk_bits, cnt_gt;
    double sum_gt;

    if (fast) {
        // ---- 3-level radix select over ubits[0..n) in LDS ----
        #pragma unroll
        for (int i = 0; i < 16; ++i) hist[t + (i << 8)] = 0u;
        __syncthreads();
        for (unsigned int i = t; i < n; i += THREADS)
            atomicAdd(&hist[ubits[i] >> 20], 1u);
        __syncthreads();
        select_bin(hist, 4096, K_TOP, wtot, wsuf, &s_bin, &s_cnt, t);
        const unsigned int b1 = s_bin;
        cnt_gt = s_cnt;
        const unsigned int K2 = K_TOP - s_cnt;

        #pragma unroll
        for (int i = 0; i < 16; ++i) hist[t + (i << 8)] = 0u;
        __syncthreads();
        for (unsigned int i = t; i < n; i += THREADS) {
            const unsigned int u = ubits[i];
            if ((u >> 20) == b1) atomicAdd(&hist[(u >> 8) & 0xFFFu], 1u);
        }
        __syncthreads();
        select_bin(hist, 4096, K2, wtot, wsuf, &s_bin, &s_cnt, t);
        const unsigned int b2 = s_bin;
        const unsigned int K3 = K2 - s_cnt;
        const unsigned int pfx24 = (b1 << 12) | b2;
        cnt_gt += s_cnt;

        hist[t] = 0u;
        __syncthreads();
        for (unsigned int i = t; i < n; i += THREADS) {
            const unsigned int u = ubits[i];
            if ((u >> 8) == pfx24) atomicAdd(&hist[u & 0xFFu], 1u);
        }
        __syncthreads();
        select_bin(hist, 256, K3, wtot, wsuf, &s_bin, &s_cnt, t);
        cnt_gt += s_cnt;
        vk_bits = (pfx24 << 8) | s_bin;

        double sg = 0.0;
        for (unsigned int i = t; i < n; i += THREADS) {
            const unsigned int u = ubits[i];
            if (u > vk_bits) sg += (double)__uint_as_float(u);
        }
        sum_gt = block_sum_double(sg, dred, t);
    } else {
        // ---- exact fallback: 4-pass radix select from global (L3-hot) ----
        #pragma unroll
        for (int i = 0; i < 16; ++i) hist[t + (i << 8)] = 0u;
        __syncthreads();
        for (int nn = 0; nn < N_DIM; ++nn) {
            const float4 q = x4[((size_t)((nn << 8) + c) << 8) + t];
            const float a0 = fabsf(q.x - mean), a1 = fabsf(q.y - mean);
            const float a2 = fabsf(q.z - mean), a3 = fabsf(q.w - mean);
            atomicAdd(&hist[__float_as_uint(a0) >> 20], 1u);
            atomicAdd(&hist[__float_as_uint(a1) >> 20], 1u);
            atomicAdd(&hist[__float_as_uint(a2) >> 20], 1u);
            atomicAdd(&hist[__float_as_uint(a3) >> 20], 1u);
        }
        __syncthreads();
        select_bin(hist, 4096, K_TOP, wtot, wsuf, &s_bin, &s_cnt, t);
        const unsigned int b1 = s_bin;
        cnt_gt = s_cnt;
        const unsigned int K2 = K_TOP - s_cnt;

        #pragma unroll
        for (int i = 0; i < 16; ++i) hist[t + (i << 8)] = 0u;
        __syncthreads();
        for (int nn = 0; nn < N_DIM; ++nn) {
            const float4 q = x4[((size_t)((nn << 8) + c) << 8) + t];
            const float vv[4] = {q.x, q.y, q.z, q.w};
            #pragma unroll
            for (int j = 0; j < 4; ++j) {
                const unsigned int u = __float_as_uint(fabsf(vv[j] - mean));
                if ((u >> 20) == b1) atomicAdd(&hist[(u >> 8) & 0xFFFu], 1u);
            }
        }
        __syncthreads();
        select_bin(hist, 4096, K2, wtot, wsuf, &s_bin, &s_cnt, t);
        const unsigned int b2 = s_bin;
        const unsigned int K3 = K2 - s_cnt;
        const unsigned int pfx24 = (b1 << 12) | b2;
        cnt_gt += s_cnt;

        hist[t] = 0u;
        __syncthreads();
        for (int nn = 0; nn < N_DIM; ++nn) {
            const float4 q = x4[((size_t)((nn << 8) + c) << 8) + t];
            const float vv[4] = {q.x, q.y, q.z, q.w};
            #pragma unroll
            for (int j = 0; j < 4; ++j) {
                const unsigned int u = __float_as_uint(fabsf(vv[j] - mean));
                if ((u >> 8) == pfx24) atomicAdd(&hist[u & 0xFFu], 1u);
            }
        }
        __syncthreads();
        select_bin(hist, 256, K3, wtot, wsuf, &s_bin, &s_cnt, t);
        cnt_gt += s_cnt;
        vk_bits = (pfx24 << 8) | s_bin;

        double sg = 0.0;
        for (int nn = 0; nn < N_DIM; ++nn) {
            const float4 q = x4[((size_t)((nn << 8) + c) << 8) + t];
            const float vv[4] = {q.x, q.y, q.z, q.w};
            #pragma unroll
            for (int j = 0; j < 4; ++j) {
                const float a = fabsf(vv[j] - mean);
                if (__float_as_uint(a) > vk_bits) sg += (double)a;
            }
        }
        sum_gt = block_sum_double(sg, dred, t);
    }

    if (t == 0) {
        const float vK = __uint_as_float(vk_bits);
        const double top_sum = sum_gt + (double)(K_TOP - cnt_gt) * (double)vK;
        const float mean_topk = (float)(top_sum / (double)K_TOP) * cconst;
        const float scale = 1.0f / (mean_topk + EPS_F);
        const float a = scale * weight[c];
        ab[c] = a;
        ab[C_DIM + c] = bias[c] - mean * a;
    }
}

// ---------------------------------------------------------------------------
// A: out = x*alpha[c] + beta[c]; x from L3; nontemporal stores.
// ---------------------------------------------------------------------------
__global__ __launch_bounds__(THREADS) void apply_pass(
    const float4* __restrict__ x4, const float* __restrict__ ab,
    float4* __restrict__ out4)
{
    __shared__ float sa[C_DIM], sb[C_DIM];
    sa[threadIdx.x] = ab[threadIdx.x];
    sb[threadIdx.x] = ab[C_DIM + threadIdx.x];
    __syncthreads();
    size_t i = (size_t)blockIdx.x * THREADS + threadIdx.x;
    #pragma unroll
    for (int k = 0; k < 8; ++k) {
        const int c = (int)((i >> 8) & (C_DIM - 1));
        const float a = sa[c], b = sb[c];
        const float4 q = x4[i];
        f4v o;
        o[0] = fmaf(q.x, a, b);
        o[1] = fmaf(q.y, a, b);
        o[2] = fmaf(q.z, a, b);
        o[3] = fmaf(q.w, a, b);
        __builtin_nontemporal_store(o, (f4v*)(out4 + i));
        i += (size_t)ABLOCKS * THREADS;
    }
}

// ---------------------------------------------------------------------------
extern "C" void kernel_launch(void* const* d_in, const int* in_sizes, int n_in,
                              void* d_out, int out_size, void* d_ws, size_t ws_size,
                              hipStream_t stream)
{
    const float* x = (const float*)d_in[0];
    const float* w = (const float*)d_in[1];
    const float* b = (const float*)d_in[2];
    float* out = (float*)d_out;

    unsigned int* cnt  = (unsigned int*)((char*)d_ws + WS_CNT_OFF);
    double*  partial   = (double*)((char*)d_ws + WS_PART_OFF);
    float*   ab        = (float*)((char*)d_ws + WS_AB_OFF);
    unsigned int* cand = (unsigned int*)((char*)d_ws + WS_CAND_OFF);

    unsigned int cap2 = 0;
    if (ws_size > WS_CAND_OFF + 4096)
        cap2 = (unsigned int)(((ws_size - WS_CAND_OFF) / (C_DIM * sizeof(unsigned int))));
    if (cap2 > MAXCAP) cap2 = MAXCAP;

    const int M = in_sizes[0] / in_sizes[1];   // 65536
    const double cst = 0.5 * (1.0 + sqrt(M_PI * log(4.0))) / sqrt(2.0 * log((double)M));

    hipMemsetAsync(cnt, 0, C_DIM * sizeof(unsigned int), stream);
    stats_pass<<<SBLOCKS, THREADS, 0, stream>>>((const float4*)x, partial, cnt, cand, cap2);
    select_pass<<<C_DIM, THREADS, 0, stream>>>((const float4*)x, partial, cnt, cand,
                                               cap2, w, b, ab, (float)cst);
    apply_pass<<<ABLOCKS, THREADS, 0, stream>>>((const float4*)x, ab, (float4*)out);
}

// Round 7
// 142.968 us; speedup vs baseline: 1.4427x; 1.4427x over previous
//
#include <hip/hip_runtime.h>
#include <math.h>

// x: [64, 256, 32, 32] fp32.
// 3-kernel pipeline, all phases at full occupancy:
//  S: 2048 blocks x 256 — partial channel sums + threshold-candidates batched
//     in LDS, ONE global atomic per block (round-6 lesson: per-candidate
//     same-address global atomics serialized the whole kernel, 81 us).
//  T:  256 blocks x 256 — mean, exact select of v_K among candidates (LDS),
//     validity proven exactly, global fallback; -> alpha/beta.
//  A: 2048 blocks x 256 — out = x*alpha + beta (x L3-hot), nontemporal stores.
#define C_DIM    256
#define N_DIM    64
#define M_DIM    65536
#define K_TOP    100
#define EPS_F    1e-7f
#define THREADS  256
#define NWAVES   4
#define T_FAST   2.5f           // candidate threshold; validity checked exactly
#define SBLOCKS  2048
#define ABLOCKS  2048
#define MAXCAP   4096u
#define LCAP     1024u          // per-block LDS candidate cap (expect ~100)

// ws layout (bytes)
#define WS_CNT_OFF   0          // 256 u32   per-channel candidate counters
#define WS_PART_OFF  1024       // 2048 dbl  per-S-block partial sums
#define WS_AB_OFF    17408      // 512 f32   alpha[256] ++ beta[256]
#define WS_CAND_OFF  20480      // 256 * cap2 u32 candidate raw-bits

typedef float f4v __attribute__((ext_vector_type(4)));

// Wave-aggregated LDS append: pred lanes write bits to buf in lane order.
// All 64 lanes of the wave must reach this call.
__device__ __forceinline__ void wave_append(
    bool pred, unsigned int bits, unsigned int* buf, unsigned int cap,
    unsigned int* counter, int lane)
{
    unsigned long long mask = __ballot(pred);
    if (mask == 0ull) return;                     // wave-uniform early out
    const int leader = __ffsll((unsigned long long)mask) - 1;
    unsigned int wbase = 0u;
    if (lane == leader) wbase = atomicAdd(counter, (unsigned int)__popcll(mask));
    wbase = __shfl(wbase, leader, 64);
    if (pred) {
        unsigned int p = wbase + (unsigned int)__popcll(mask & ((1ull << lane) - 1ull));
        if (p < cap) buf[p] = bits;
    }
}

__device__ __forceinline__ unsigned int wave_suffix_u32(unsigned int v, int lane)
{
    #pragma unroll
    for (int off = 1; off < 64; off <<= 1) {
        unsigned int o = __shfl_down(v, off, 64);
        if (lane + off < 64) v += o;
    }
    return v;   // suffix-inclusive sum over lanes >= lane
}

__device__ __forceinline__ double block_sum_double(double v, double* dred, int tid)
{
    const int lane = tid & 63, wv = tid >> 6;
    #pragma unroll
    for (int off = 1; off < 64; off <<= 1) {
        double o = __shfl_down(v, off, 64);
        if (lane + off < 64) v += o;
    }
    __syncthreads();
    if (lane == 0) dred[wv] = v;
    __syncthreads();
    double r = 0.0;
    if (tid == 0) {
        #pragma unroll
        for (int i = 0; i < NWAVES; ++i) r += dred[i];
    }
    return r;   // valid on tid 0 only
}

// Find, in hist[0..nbins) (ascending bins), the bin holding the Krem-th
// largest element; write bin + count-strictly-above into LDS outs.
__device__ __forceinline__ void select_bin(
    const unsigned int* hist, int nbins, unsigned int Krem,
    unsigned int* wtot, unsigned int* wsuf,
    unsigned int* out_bin, unsigned int* out_cnt, int tid)
{
    const int lane = tid & 63, wv = tid >> 6;
    const int bpt = (nbins + THREADS - 1) / THREADS;
    const int lo = tid * bpt;
    const int hi = min(nbins, lo + bpt);
    unsigned int s = 0;
    for (int b = lo; b < hi; ++b) s += hist[b];
    const unsigned int ws = wave_suffix_u32(s, lane);
    if (lane == 0) wtot[wv] = ws;
    __syncthreads();
    if (tid < NWAVES) {
        unsigned int t2 = 0;
        for (int j = tid; j < NWAVES; ++j) t2 += wtot[j];
        wsuf[tid] = t2;
    }
    __syncthreads();
    const unsigned int above_w = (wv + 1 < NWAVES) ? wsuf[wv + 1] : 0u;
    const unsigned int incl   = ws + above_w;
    const unsigned int S_excl = incl - s;
    if (S_excl < Krem && incl >= Krem) {     // exactly one thread
        unsigned int cum = S_excl;
        for (int b = hi - 1; b >= lo; --b) {
            unsigned int h = hist[b];
            if (cum + h >= Krem) { *out_bin = (unsigned int)b; *out_cnt = cum; break; }
            cum += h;
        }
    }
    __syncthreads();
}

// ---------------------------------------------------------------------------
// S: block b -> channel c=b&255, slabs n=8g..8g+7 (g=b>>8).
// Thread t reads float4 (n*256+c)*256 + t. Candidates -> LDS; one flush.
// ---------------------------------------------------------------------------
__global__ __launch_bounds__(THREADS) void stats_pass(
    const float4* __restrict__ x4, double* __restrict__ partial,
    unsigned int* __restrict__ cnt, unsigned int* __restrict__ candbuf,
    unsigned int cap2)
{
    const int b = blockIdx.x;
    const int c = b & 255;
    const int g = b >> 8;
    const int t = threadIdx.x;
    const int lane = t & 63, wv = t >> 6;

    __shared__ double dred[NWAVES];
    __shared__ unsigned int lbuf[LCAP];
    __shared__ unsigned int s_lc, s_base;
    if (t == 0) s_lc = 0u;
    __syncthreads();

    double s = 0.0;
    #pragma unroll
    for (int j = 0; j < 8; ++j) {
        const int n = (g << 3) + j;
        const float4 q = x4[((size_t)((n << 8) + c) << 8) + t];
        s += ((double)q.x + (double)q.y) + ((double)q.z + (double)q.w);
        wave_append(fabsf(q.x) >= T_FAST, __float_as_uint(q.x), lbuf, LCAP, &s_lc, lane);
        wave_append(fabsf(q.y) >= T_FAST, __float_as_uint(q.y), lbuf, LCAP, &s_lc, lane);
        wave_append(fabsf(q.z) >= T_FAST, __float_as_uint(q.z), lbuf, LCAP, &s_lc, lane);
        wave_append(fabsf(q.w) >= T_FAST, __float_as_uint(q.w), lbuf, LCAP, &s_lc, lane);
    }
    #pragma unroll
    for (int off = 1; off < 64; off <<= 1) {
        double o = __shfl_down(s, off, 64);
        if (lane + off < 64) s += o;
    }
    if (lane == 0) dred[wv] = s;
    __syncthreads();
    if (t == 0) {
        partial[b] = (dred[0] + dred[1]) + (dred[2] + dred[3]);
        // Reserve a range with ONE global atomic. If the LDS buffer
        // overflowed, poison the count so T provably takes the fallback.
        unsigned int add = (s_lc > LCAP) ? (MAXCAP + 1u) : s_lc;
        s_base = atomicAdd(&cnt[c], add);
    }
    __syncthreads();
    const unsigned int lc = min(s_lc, LCAP);
    const unsigned int base = s_base;
    if (s_lc <= LCAP) {
        unsigned int* dst = candbuf + (size_t)c * cap2;
        for (unsigned int i = t; i < lc; i += THREADS) {
            const unsigned int p = base + i;
            if (p < cap2) dst[p] = lbuf[i];
        }
    }
}

// ---------------------------------------------------------------------------
// T: per-channel select. One 256-thread block per channel.
// ---------------------------------------------------------------------------
__global__ __launch_bounds__(THREADS) void select_pass(
    const float4* __restrict__ x4, const double* __restrict__ partial,
    const unsigned int* __restrict__ cnt, const unsigned int* __restrict__ candbuf,
    unsigned int cap2,
    const float* __restrict__ weight, const float* __restrict__ bias,
    float* __restrict__ ab, float cconst)
{
    const int c = blockIdx.x;
    const int t = threadIdx.x;

    __shared__ unsigned int ubits[MAXCAP];
    __shared__ unsigned int hist[4096];
    __shared__ unsigned int wtot[NWAVES], wsuf[NWAVES];
    __shared__ double dred[NWAVES > 8 ? NWAVES : 8];
    __shared__ float s_mean;
    __shared__ unsigned int s_bin, s_cnt, s_nB;

    if (t < 8) dred[t] = partial[(t << 8) + c];
    if (t == 0) s_nB = 0u;
    __syncthreads();
    if (t == 0) {
        double m = 0.0;
        #pragma unroll
        for (int i = 0; i < 8; ++i) m += dred[i];
        s_mean = (float)(m / (double)M_DIM);
    }
    __syncthreads();
    const float mean = s_mean;
    const float Babs = T_FAST + fabsf(mean);
    const unsigned int Bbits = __float_as_uint(Babs);
    const unsigned int n = cnt[c];

    // Validity: non-collected values have |x-mean| < Babs; if >= K collected
    // values exceed Babs (strict), the global top-K is inside the collection.
    bool fast = (n <= cap2);
    if (fast) {
        unsigned int loc = 0;
        for (unsigned int i = t; i < n; i += THREADS) {
            const float v = __uint_as_float(candbuf[(size_t)c * cap2 + i]);
            const unsigned int u = __float_as_uint(fabsf(v - mean));
            ubits[i] = u;
            if (u > Bbits) ++loc;
        }
        if (loc) atomicAdd(&s_nB, loc);
        __syncthreads();
        fast = (s_nB >= K_TOP);
    }

    unsigned int vk_bits, cnt_gt;
    double sum_gt;

    if (fast) {
        // ---- 3-level radix select over ubits[0..n) in LDS ----
        #pragma unroll
        for (int i = 0; i < 16; ++i) hist[t + (i << 8)] = 0u;
        __syncthreads();
        for (unsigned int i = t; i < n; i += THREADS)
            atomicAdd(&hist[ubits[i] >> 20], 1u);
        __syncthreads();
        select_bin(hist, 4096, K_TOP, wtot, wsuf, &s_bin, &s_cnt, t);
        const unsigned int b1 = s_bin;
        cnt_gt = s_cnt;
        const unsigned int K2 = K_TOP - s_cnt;

        #pragma unroll
        for (int i = 0; i < 16; ++i) hist[t + (i << 8)] = 0u;
        __syncthreads();
        for (unsigned int i = t; i < n; i += THREADS) {
            const unsigned int u = ubits[i];
            if ((u >> 20) == b1) atomicAdd(&hist[(u >> 8) & 0xFFFu], 1u);
        }
        __syncthreads();
        select_bin(hist, 4096, K2, wtot, wsuf, &s_bin, &s_cnt, t);
        const unsigned int b2 = s_bin;
        const unsigned int K3 = K2 - s_cnt;
        const unsigned int pfx24 = (b1 << 12) | b2;
        cnt_gt += s_cnt;

        hist[t] = 0u;
        __syncthreads();
        for (unsigned int i = t; i < n; i += THREADS) {
            const unsigned int u = ubits[i];
            if ((u >> 8) == pfx24) atomicAdd(&hist[u & 0xFFu], 1u);
        }
        __syncthreads();
        select_bin(hist, 256, K3, wtot, wsuf, &s_bin, &s_cnt, t);
        cnt_gt += s_cnt;
        vk_bits = (pfx24 << 8) | s_bin;

        double sg = 0.0;
        for (unsigned int i = t; i < n; i += THREADS) {
            const unsigned int u = ubits[i];
            if (u > vk_bits) sg += (double)__uint_as_float(u);
        }
        sum_gt = block_sum_double(sg, dred, t);
    } else {
        // ---- exact fallback: 4-pass radix select from global (L3-hot) ----
        #pragma unroll
        for (int i = 0; i < 16; ++i) hist[t + (i << 8)] = 0u;
        __syncthreads();
        for (int nn = 0; nn < N_DIM; ++nn) {
            const float4 q = x4[((size_t)((nn << 8) + c) << 8) + t];
            const float vv[4] = {q.x, q.y, q.z, q.w};
            #pragma unroll
            for (int j = 0; j < 4; ++j)
                atomicAdd(&hist[__float_as_uint(fabsf(vv[j] - mean)) >> 20], 1u);
        }
        __syncthreads();
        select_bin(hist, 4096, K_TOP, wtot, wsuf, &s_bin, &s_cnt, t);
        const unsigned int b1 = s_bin;
        cnt_gt = s_cnt;
        const unsigned int K2 = K_TOP - s_cnt;

        #pragma unroll
        for (int i = 0; i < 16; ++i) hist[t + (i << 8)] = 0u;
        __syncthreads();
        for (int nn = 0; nn < N_DIM; ++nn) {
            const float4 q = x4[((size_t)((nn << 8) + c) << 8) + t];
            const float vv[4] = {q.x, q.y, q.z, q.w};
            #pragma unroll
            for (int j = 0; j < 4; ++j) {
                const unsigned int u = __float_as_uint(fabsf(vv[j] - mean));
                if ((u >> 20) == b1) atomicAdd(&hist[(u >> 8) & 0xFFFu], 1u);
            }
        }
        __syncthreads();
        select_bin(hist, 4096, K2, wtot, wsuf, &s_bin, &s_cnt, t);
        const unsigned int b2 = s_bin;
        const unsigned int K3 = K2 - s_cnt;
        const unsigned int pfx24 = (b1 << 12) | b2;
        cnt_gt += s_cnt;

        hist[t] = 0u;
        __syncthreads();
        for (int nn = 0; nn < N_DIM; ++nn) {
            const float4 q = x4[((size_t)((nn << 8) + c) << 8) + t];
            const float vv[4] = {q.x, q.y, q.z, q.w};
            #pragma unroll
            for (int j = 0; j < 4; ++j) {
                const unsigned int u = __float_as_uint(fabsf(vv[j] - mean));
                if ((u >> 8) == pfx24) atomicAdd(&hist[u & 0xFFu], 1u);
            }
        }
        __syncthreads();
        select_bin(hist, 256, K3, wtot, wsuf, &s_bin, &s_cnt, t);
        cnt_gt += s_cnt;
        vk_bits = (pfx24 << 8) | s_bin;

        double sg = 0.0;
        for (int nn = 0; nn < N_DIM; ++nn) {
            const float4 q = x4[((size_t)((nn << 8) + c) << 8) + t];
            const float vv[4] = {q.x, q.y, q.z, q.w};
            #pragma unroll
            for (int j = 0; j < 4; ++j) {
                const float a = fabsf(vv[j] - mean);
                if (__float_as_uint(a) > vk_bits) sg += (double)a;
            }
        }
        sum_gt = block_sum_double(sg, dred, t);
    }

    if (t == 0) {
        const float vK = __uint_as_float(vk_bits);
        const double top_sum = sum_gt + (double)(K_TOP - cnt_gt) * (double)vK;
        const float mean_topk = (float)(top_sum / (double)K_TOP) * cconst;
        const float scale = 1.0f / (mean_topk + EPS_F);
        const float a = scale * weight[c];
        ab[c] = a;
        ab[C_DIM + c] = bias[c] - mean * a;
    }
}

// ---------------------------------------------------------------------------
// A: out = x*alpha[c] + beta[c]; x from L3; nontemporal stores.
// ---------------------------------------------------------------------------
__global__ __launch_bounds__(THREADS) void apply_pass(
    const float4* __restrict__ x4, const float* __restrict__ ab,
    float4* __restrict__ out4)
{
    __shared__ float sa[C_DIM], sb[C_DIM];
    sa[threadIdx.x] = ab[threadIdx.x];
    sb[threadIdx.x] = ab[C_DIM + threadIdx.x];
    __syncthreads();
    size_t i = (size_t)blockIdx.x * THREADS + threadIdx.x;
    #pragma unroll
    for (int k = 0; k < 8; ++k) {
        const int c = (int)((i >> 8) & (C_DIM - 1));
        const float a = sa[c], b = sb[c];
        const float4 q = x4[i];
        f4v o;
        o[0] = fmaf(q.x, a, b);
        o[1] = fmaf(q.y, a, b);
        o[2] = fmaf(q.z, a, b);
        o[3] = fmaf(q.w, a, b);
        __builtin_nontemporal_store(o, (f4v*)(out4 + i));
        i += (size_t)ABLOCKS * THREADS;
    }
}

// ---------------------------------------------------------------------------
extern "C" void kernel_launch(void* const* d_in, const int* in_sizes, int n_in,
                              void* d_out, int out_size, void* d_ws, size_t ws_size,
                              hipStream_t stream)
{
    const float* x = (const float*)d_in[0];
    const float* w = (const float*)d_in[1];
    const float* b = (const float*)d_in[2];
    float* out = (float*)d_out;

    unsigned int* cnt  = (unsigned int*)((char*)d_ws + WS_CNT_OFF);
    double*  partial   = (double*)((char*)d_ws + WS_PART_OFF);
    float*   ab        = (float*)((char*)d_ws + WS_AB_OFF);
    unsigned int* cand = (unsigned int*)((char*)d_ws + WS_CAND_OFF);

    unsigned int cap2 = 0;
    if (ws_size > WS_CAND_OFF + 4096)
        cap2 = (unsigned int)((ws_size - WS_CAND_OFF) / (C_DIM * sizeof(unsigned int)));
    if (cap2 > MAXCAP) cap2 = MAXCAP;

    const int M = in_sizes[0] / in_sizes[1];   // 65536
    const double cst = 0.5 * (1.0 + sqrt(M_PI * log(4.0))) / sqrt(2.0 * log((double)M));

    hipMemsetAsync(cnt, 0, C_DIM * sizeof(unsigned int), stream);
    stats_pass<<<SBLOCKS, THREADS, 0, stream>>>((const float4*)x, partial, cnt, cand, cap2);
    select_pass<<<C_DIM, THREADS, 0, stream>>>((const float4*)x, partial, cnt, cand,
                                               cap2, w, b, ab, (float)cst);
    apply_pass<<<ABLOCKS, THREADS, 0, stream>>>((const float4*)x, ab, (float4*)out);
}

// Round 8
// 142.896 us; speedup vs baseline: 1.4434x; 1.0005x over previous
//
#include <hip/hip_runtime.h>
#include <math.h>

// x: [64, 256, 32, 32] fp32. 3-kernel pipeline, zero global atomics:
//  S: 2048 blocks x 256 — per-block partial sums + threshold-candidates into
//     a PRIVATE per-block region (plain stores; r7 lesson: even one atomic
//     reservation per block serializes across same-channel blocks).
//  T:  256 blocks x 256 — mean; gather 8 regions (L2-hot); exact radix select
//     of v_K + topK sum in LDS; validity proven exactly; global fallback.
//  A: 2048 blocks x 256 — out = x*alpha + beta; x L3-hot; nontemporal stores.
#define C_DIM    256
#define N_DIM    64
#define M_DIM    65536
#define K_TOP    100
#define EPS_F    1e-7f
#define THREADS  256
#define NWAVES   4
#define T_FAST   2.5f           // candidate threshold; validity checked exactly
#define SBLOCKS  2048
#define ABLOCKS  2048
#define MAXCAP   4096u          // T's LDS staging capacity (total per channel)
#define LCAP     768u           // per-block LDS candidate cap (expect ~100)

// ws layout (bytes)
#define WS_PART_OFF  0          // 2048 dbl  per-S-block partial sums   (16 KB)
#define WS_BCNT_OFF  16384      // 2048 u32  per-S-block candidate counts (8 KB)
#define WS_AB_OFF    24576      // 512 f32   alpha[256] ++ beta[256]     (2 KB)
#define WS_CAND_OFF  32768      // 2048 * bcap u32 private candidate regions

typedef float f4v __attribute__((ext_vector_type(4)));

// Wave-aggregated LDS append: pred lanes write bits to buf in lane order.
__device__ __forceinline__ void wave_append(
    bool pred, unsigned int bits, unsigned int* buf, unsigned int cap,
    unsigned int* counter, int lane)
{
    unsigned long long mask = __ballot(pred);
    if (mask == 0ull) return;                     // wave-uniform early out
    const int leader = __ffsll((unsigned long long)mask) - 1;
    unsigned int wbase = 0u;
    if (lane == leader) wbase = atomicAdd(counter, (unsigned int)__popcll(mask));
    wbase = __shfl(wbase, leader, 64);
    if (pred) {
        unsigned int p = wbase + (unsigned int)__popcll(mask & ((1ull << lane) - 1ull));
        if (p < cap) buf[p] = bits;
    }
}

__device__ __forceinline__ unsigned int wave_suffix_u32(unsigned int v, int lane)
{
    #pragma unroll
    for (int off = 1; off < 64; off <<= 1) {
        unsigned int o = __shfl_down(v, off, 64);
        if (lane + off < 64) v += o;
    }
    return v;
}

__device__ __forceinline__ double block_sum_double(double v, double* dred, int tid)
{
    const int lane = tid & 63, wv = tid >> 6;
    #pragma unroll
    for (int off = 1; off < 64; off <<= 1) {
        double o = __shfl_down(v, off, 64);
        if (lane + off < 64) v += o;
    }
    __syncthreads();
    if (lane == 0) dred[wv] = v;
    __syncthreads();
    double r = 0.0;
    if (tid == 0) {
        #pragma unroll
        for (int i = 0; i < NWAVES; ++i) r += dred[i];
    }
    return r;   // valid on tid 0 only
}

// Find, in hist[0..nbins) (ascending bins), the bin holding the Krem-th
// largest element; write bin + count-strictly-above into LDS outs.
__device__ __forceinline__ void select_bin(
    const unsigned int* hist, int nbins, unsigned int Krem,
    unsigned int* wtot, unsigned int* wsuf,
    unsigned int* out_bin, unsigned int* out_cnt, int tid)
{
    const int lane = tid & 63, wv = tid >> 6;
    const int bpt = (nbins + THREADS - 1) / THREADS;
    const int lo = tid * bpt;
    const int hi = min(nbins, lo + bpt);
    unsigned int s = 0;
    for (int b = lo; b < hi; ++b) s += hist[b];
    const unsigned int ws = wave_suffix_u32(s, lane);
    if (lane == 0) wtot[wv] = ws;
    __syncthreads();
    if (tid < NWAVES) {
        unsigned int t2 = 0;
        for (int j = tid; j < NWAVES; ++j) t2 += wtot[j];
        wsuf[tid] = t2;
    }
    __syncthreads();
    const unsigned int above_w = (wv + 1 < NWAVES) ? wsuf[wv + 1] : 0u;
    const unsigned int incl   = ws + above_w;
    const unsigned int S_excl = incl - s;
    if (S_excl < Krem && incl >= Krem) {     // exactly one thread
        unsigned int cum = S_excl;
        for (int b = hi - 1; b >= lo; --b) {
            unsigned int h = hist[b];
            if (cum + h >= Krem) { *out_bin = (unsigned int)b; *out_cnt = cum; break; }
            cum += h;
        }
    }
    __syncthreads();
}

// ---------------------------------------------------------------------------
// S: block b -> channel c=b&255, slabs n=8g..8g+7 (g=b>>8).
// Candidates -> LDS -> private region candbuf[b*bcap]; count -> bcnt[b].
// No global atomics, no prior initialization required.
// ---------------------------------------------------------------------------
__global__ __launch_bounds__(THREADS) void stats_pass(
    const float4* __restrict__ x4, double* __restrict__ partial,
    unsigned int* __restrict__ bcnt, unsigned int* __restrict__ candbuf,
    unsigned int bcap)
{
    const int b = blockIdx.x;
    const int c = b & 255;
    const int g = b >> 8;
    const int t = threadIdx.x;
    const int lane = t & 63, wv = t >> 6;
    const unsigned int capw = (bcap < LCAP) ? bcap : LCAP;

    __shared__ double dred[NWAVES];
    __shared__ unsigned int lbuf[LCAP];
    __shared__ unsigned int s_lc;
    if (t == 0) s_lc = 0u;
    __syncthreads();

    double s = 0.0;
    #pragma unroll
    for (int j = 0; j < 8; ++j) {
        const int n = (g << 3) + j;
        const float4 q = x4[((size_t)((n << 8) + c) << 8) + t];
        s += ((double)q.x + (double)q.y) + ((double)q.z + (double)q.w);
        wave_append(fabsf(q.x) >= T_FAST, __float_as_uint(q.x), lbuf, capw, &s_lc, lane);
        wave_append(fabsf(q.y) >= T_FAST, __float_as_uint(q.y), lbuf, capw, &s_lc, lane);
        wave_append(fabsf(q.z) >= T_FAST, __float_as_uint(q.z), lbuf, capw, &s_lc, lane);
        wave_append(fabsf(q.w) >= T_FAST, __float_as_uint(q.w), lbuf, capw, &s_lc, lane);
    }
    #pragma unroll
    for (int off = 1; off < 64; off <<= 1) {
        double o = __shfl_down(s, off, 64);
        if (lane + off < 64) s += o;
    }
    if (lane == 0) dred[wv] = s;
    __syncthreads();
    if (t == 0) {
        partial[b] = (dred[0] + dred[1]) + (dred[2] + dred[3]);
        bcnt[b] = s_lc;                       // raw count (may exceed capw)
    }
    __syncthreads();
    const unsigned int lc = min(s_lc, capw);
    unsigned int* dst = candbuf + (size_t)b * bcap;
    for (unsigned int i = t; i < lc; i += THREADS) dst[i] = lbuf[i];
}

// ---------------------------------------------------------------------------
// T: per-channel select. One 256-thread block per channel.
// ---------------------------------------------------------------------------
__global__ __launch_bounds__(THREADS) void select_pass(
    const float4* __restrict__ x4, const double* __restrict__ partial,
    const unsigned int* __restrict__ bcnt, const unsigned int* __restrict__ candbuf,
    unsigned int bcap,
    const float* __restrict__ weight, const float* __restrict__ bias,
    float* __restrict__ ab, float cconst)
{
    const int c = blockIdx.x;
    const int t = threadIdx.x;
    const unsigned int capw = (bcap < LCAP) ? bcap : LCAP;

    __shared__ unsigned int ubits[MAXCAP];
    __shared__ unsigned int hist[4096];
    __shared__ unsigned int wtot[NWAVES], wsuf[NWAVES];
    __shared__ double dred[8];
    __shared__ float s_mean;
    __shared__ unsigned int s_bin, s_cnt, s_nB;
    __shared__ unsigned int s_bc[8], s_off[9];
    __shared__ int s_ok;

    if (t < 8) {
        dred[t] = partial[(t << 8) + c];
        s_bc[t] = bcnt[(t << 8) + c];
    }
    if (t == 0) s_nB = 0u;
    __syncthreads();
    if (t == 0) {
        double m = 0.0;
        #pragma unroll
        for (int i = 0; i < 8; ++i) m += dred[i];
        s_mean = (float)(m / (double)M_DIM);
        unsigned int off = 0;
        int ok = 1;
        #pragma unroll
        for (int g = 0; g < 8; ++g) {
            s_off[g] = off;
            if (s_bc[g] > capw) ok = 0;
            off += min(s_bc[g], capw);
        }
        s_off[8] = off;
        if (off > MAXCAP) ok = 0;
        s_ok = ok;
    }
    __syncthreads();
    const float mean = s_mean;
    const float Babs = T_FAST + fabsf(mean);
    const unsigned int Bbits = __float_as_uint(Babs);
    const unsigned int n = s_off[8];

    // Gather candidates from the 8 private regions; count those > Babs.
    bool fast = (s_ok != 0);
    if (fast) {
        unsigned int loc = 0;
        #pragma unroll
        for (int g = 0; g < 8; ++g) {
            const unsigned int cg = min(s_bc[g], capw);
            const unsigned int* src = candbuf + (size_t)((g << 8) + c) * bcap;
            const unsigned int base = s_off[g];
            for (unsigned int i = t; i < cg; i += THREADS) {
                const float v = __uint_as_float(src[i]);
                const unsigned int u = __float_as_uint(fabsf(v - mean));
                ubits[base + i] = u;
                if (u > Bbits) ++loc;
            }
        }
        if (loc) atomicAdd(&s_nB, loc);
        __syncthreads();
        // Validity: non-collected values have |x-mean| < Babs; if >= K
        // collected values strictly exceed Babs, top-K is fully collected.
        fast = (s_nB >= K_TOP);
    }

    unsigned int vk_bits, cnt_gt;
    double sum_gt;

    if (fast) {
        // ---- 3-level radix select over ubits[0..n) in LDS ----
        #pragma unroll
        for (int i = 0; i < 16; ++i) hist[t + (i << 8)] = 0u;
        __syncthreads();
        for (unsigned int i = t; i < n; i += THREADS)
            atomicAdd(&hist[ubits[i] >> 20], 1u);
        __syncthreads();
        select_bin(hist, 4096, K_TOP, wtot, wsuf, &s_bin, &s_cnt, t);
        const unsigned int b1 = s_bin;
        cnt_gt = s_cnt;
        const unsigned int K2 = K_TOP - s_cnt;

        #pragma unroll
        for (int i = 0; i < 16; ++i) hist[t + (i << 8)] = 0u;
        __syncthreads();
        for (unsigned int i = t; i < n; i += THREADS) {
            const unsigned int u = ubits[i];
            if ((u >> 20) == b1) atomicAdd(&hist[(u >> 8) & 0xFFFu], 1u);
        }
        __syncthreads();
        select_bin(hist, 4096, K2, wtot, wsuf, &s_bin, &s_cnt, t);
        const unsigned int b2 = s_bin;
        const unsigned int K3 = K2 - s_cnt;
        const unsigned int pfx24 = (b1 << 12) | b2;
        cnt_gt += s_cnt;

        hist[t] = 0u;
        __syncthreads();
        for (unsigned int i = t; i < n; i += THREADS) {
            const unsigned int u = ubits[i];
            if ((u >> 8) == pfx24) atomicAdd(&hist[u & 0xFFu], 1u);
        }
        __syncthreads();
        select_bin(hist, 256, K3, wtot, wsuf, &s_bin, &s_cnt, t);
        cnt_gt += s_cnt;
        vk_bits = (pfx24 << 8) | s_bin;

        double sg = 0.0;
        for (unsigned int i = t; i < n; i += THREADS) {
            const unsigned int u = ubits[i];
            if (u > vk_bits) sg += (double)__uint_as_float(u);
        }
        sum_gt = block_sum_double(sg, dred, t);
    } else {
        // ---- exact fallback: 4-pass radix select from global (L3-hot) ----
        #pragma unroll
        for (int i = 0; i < 16; ++i) hist[t + (i << 8)] = 0u;
        __syncthreads();
        for (int nn = 0; nn < N_DIM; ++nn) {
            const float4 q = x4[((size_t)((nn << 8) + c) << 8) + t];
            const float vv[4] = {q.x, q.y, q.z, q.w};
            #pragma unroll
            for (int j = 0; j < 4; ++j)
                atomicAdd(&hist[__float_as_uint(fabsf(vv[j] - mean)) >> 20], 1u);
        }
        __syncthreads();
        select_bin(hist, 4096, K_TOP, wtot, wsuf, &s_bin, &s_cnt, t);
        const unsigned int b1 = s_bin;
        cnt_gt = s_cnt;
        const unsigned int K2 = K_TOP - s_cnt;

        #pragma unroll
        for (int i = 0; i < 16; ++i) hist[t + (i << 8)] = 0u;
        __syncthreads();
        for (int nn = 0; nn < N_DIM; ++nn) {
            const float4 q = x4[((size_t)((nn << 8) + c) << 8) + t];
            const float vv[4] = {q.x, q.y, q.z, q.w};
            #pragma unroll
            for (int j = 0; j < 4; ++j) {
                const unsigned int u = __float_as_uint(fabsf(vv[j] - mean));
                if ((u >> 20) == b1) atomicAdd(&hist[(u >> 8) & 0xFFFu], 1u);
            }
        }
        __syncthreads();
        select_bin(hist, 4096, K2, wtot, wsuf, &s_bin, &s_cnt, t);
        const unsigned int b2 = s_bin;
        const unsigned int K3 = K2 - s_cnt;
        const unsigned int pfx24 = (b1 << 12) | b2;
        cnt_gt += s_cnt;

        hist[t] = 0u;
        __syncthreads();
        for (int nn = 0; nn < N_DIM; ++nn) {
            const float4 q = x4[((size_t)((nn << 8) + c) << 8) + t];
            const float vv[4] = {q.x, q.y, q.z, q.w};
            #pragma unroll
            for (int j = 0; j < 4; ++j) {
                const unsigned int u = __float_as_uint(fabsf(vv[j] - mean));
                if ((u >> 8) == pfx24) atomicAdd(&hist[u & 0xFFu], 1u);
            }
        }
        __syncthreads();
        select_bin(hist, 256, K3, wtot, wsuf, &s_bin, &s_cnt, t);
        cnt_gt += s_cnt;
        vk_bits = (pfx24 << 8) | s_bin;

        double sg = 0.0;
        for (int nn = 0; nn < N_DIM; ++nn) {
            const float4 q = x4[((size_t)((nn << 8) + c) << 8) + t];
            const float vv[4] = {q.x, q.y, q.z, q.w};
            #pragma unroll
            for (int j = 0; j < 4; ++j) {
                const float a = fabsf(vv[j] - mean);
                if (__float_as_uint(a) > vk_bits) sg += (double)a;
            }
        }
        sum_gt = block_sum_double(sg, dred, t);
    }

    if (t == 0) {
        const float vK = __uint_as_float(vk_bits);
        const double top_sum = sum_gt + (double)(K_TOP - cnt_gt) * (double)vK;
        const float mean_topk = (float)(top_sum / (double)K_TOP) * cconst;
        const float scale = 1.0f / (mean_topk + EPS_F);
        const float a = scale * weight[c];
        ab[c] = a;
        ab[C_DIM + c] = bias[c] - mean * a;
    }
}

// ---------------------------------------------------------------------------
// A: out = x*alpha[c] + beta[c]; x from L3; nontemporal stores.
// ---------------------------------------------------------------------------
__global__ __launch_bounds__(THREADS) void apply_pass(
    const float4* __restrict__ x4, const float* __restrict__ ab,
    float4* __restrict__ out4)
{
    __shared__ float sa[C_DIM], sb[C_DIM];
    sa[threadIdx.x] = ab[threadIdx.x];
    sb[threadIdx.x] = ab[C_DIM + threadIdx.x];
    __syncthreads();
    size_t i = (size_t)blockIdx.x * THREADS + threadIdx.x;
    #pragma unroll
    for (int k = 0; k < 8; ++k) {
        const int c = (int)((i >> 8) & (C_DIM - 1));
        const float a = sa[c], b = sb[c];
        const float4 q = x4[i];
        f4v o;
        o[0] = fmaf(q.x, a, b);
        o[1] = fmaf(q.y, a, b);
        o[2] = fmaf(q.z, a, b);
        o[3] = fmaf(q.w, a, b);
        __builtin_nontemporal_store(o, (f4v*)(out4 + i));
        i += (size_t)ABLOCKS * THREADS;
    }
}

// ---------------------------------------------------------------------------
extern "C" void kernel_launch(void* const* d_in, const int* in_sizes, int n_in,
                              void* d_out, int out_size, void* d_ws, size_t ws_size,
                              hipStream_t stream)
{
    const float* x = (const float*)d_in[0];
    const float* w = (const float*)d_in[1];
    const float* b = (const float*)d_in[2];
    float* out = (float*)d_out;

    double*  partial   = (double*)((char*)d_ws + WS_PART_OFF);
    unsigned int* bcnt = (unsigned int*)((char*)d_ws + WS_BCNT_OFF);
    float*   ab        = (float*)((char*)d_ws + WS_AB_OFF);
    unsigned int* cand = (unsigned int*)((char*)d_ws + WS_CAND_OFF);

    unsigned int bcap = LCAP;
    if (ws_size > WS_CAND_OFF) {
        const size_t avail = (ws_size - WS_CAND_OFF) / ((size_t)SBLOCKS * sizeof(unsigned int));
        if (avail < bcap) bcap = (unsigned int)avail;
    } else {
        bcap = 0;
    }

    const int M = in_sizes[0] / in_sizes[1];   // 65536
    const double cst = 0.5 * (1.0 + sqrt(M_PI * log(4.0))) / sqrt(2.0 * log((double)M));

    stats_pass<<<SBLOCKS, THREADS, 0, stream>>>((const float4*)x, partial, bcnt, cand, bcap);
    select_pass<<<C_DIM, THREADS, 0, stream>>>((const float4*)x, partial, bcnt, cand,
                                               bcap, w, b, ab, (float)cst);
    apply_pass<<<ABLOCKS, THREADS, 0, stream>>>((const float4*)x, ab, (float4*)out);
}